// Round 4
// baseline (189.799 us; speedup 1.0000x reference)
//
#include <hip/hip_runtime.h>

// Conv2d 32x128x56x56 -> 32x256x56x56, 3x3, pad 1, stride 1. fp32 I/O.
// Implicit GEMM, bf16 mfma_f32_16x16x32.
// ROUND 4: prep_x DELETED -- fused into conv staging. Rounds 0-3 showed a
// ~125us residual that never responded to prep_x-internal optimization;
// fusing removes the X2 intermediate (77MB traffic) and the 6272-block
// launch entirely. Conv stages straight from NCHW fp32:
//   - wave wv owns input row h = h0-1+wv (wave-uniform halo validity),
//     16 chunks of 8ci x 56w: float4 coalesced reads -> RNE bf16 pack ->
//     per-wave 1KB LDS scratch -> u16 transpose reads -> ds_write_b128
//     into Xs. Private scratch => NO barriers in staging; ONE barrier total.
//   - Xs layout [ci_hi(4)][pixel(232)][ci_lo(32)], pixel stride 64B:
//     main-loop ds_read_b128 bank group = 4*(pix&1)+quad -> uniform 8
//     lanes/4-bank group = conflict-FREE (was 3.6M conflict cy with 272B
//     rows). No padding: LDS 59392 + 4224 scratch = 63616 B (2 blocks/CU).
//   - XCD swizzle: 896 = 8*112, each XCD gets 4 whole images -> halo
//     re-reads of x are same-XCD L2 hits.
// Main loop unchanged from round 3: 36 steps {4 A global->reg (prefetched
// one step ahead), 7 ds_read_b128, 28 MFMA}, no barriers.
// Block: 256 thr = 4 waves, tile 256co x 112p (2 output rows). Wave: 4m x 7n.

#define CIN   128
#define COUT  256
#define HWID  56
#define IMG   (HWID*HWID)     // 3136
#define NIMG  32
#define XP    32              // Xs pixel stride (shorts) = 64B
#define XCH   (232*XP)        // shorts per ci_hi plane

typedef __attribute__((ext_vector_type(8))) short short8;   // 8 bf16 = 4 VGPRs
typedef __attribute__((ext_vector_type(4))) float float4v;  // MFMA acc

__device__ __forceinline__ unsigned short f2bf(float f) {
    unsigned int u = __builtin_bit_cast(unsigned int, f);
    u += 0x7FFFu + ((u >> 16) & 1u);   // RNE
    return (unsigned short)(u >> 16);
}

// W2[((ci_hi*9 + kh*3 + kw)*256 + co)*32 + ci_lo] = bf16(w[co][ci_hi*32+ci_lo][kh][kw])
__global__ __launch_bounds__(256) void prep_w_kernel(const float* __restrict__ w,
                                                     unsigned short* __restrict__ W2) {
    int o = blockIdx.x * 256 + threadIdx.x;        // 294912 total
    int ci_lo = o & 31;
    int co    = (o >> 5) & 255;
    int s     = o >> 13;                           // 0..35
    int ci_hi = s / 9;
    int r9    = s - ci_hi * 9;                     // kh*3+kw
    W2[o] = f2bf(w[(co * CIN + ci_hi * 32 + ci_lo) * 9 + r9]);
}

__global__ __launch_bounds__(256, 2)
void conv_mfma_kernel(const float* __restrict__ x,
                      const unsigned short* __restrict__ W2,
                      float* __restrict__ out) {
    __shared__ __align__(16) unsigned short Xs[4 * XCH];   // 59392 B
    __shared__ unsigned short Ls[4][8 * 66];               // 4224 B, per-wave scratch

    const int tid  = threadIdx.x;
    const int lane = tid & 63;
    const int wv   = tid >> 6;
    const int l15  = lane & 15;
    const int quad = lane >> 4;

    // XCD swizzle: blockIdx round-robins over 8 XCDs; give each XCD a
    // contiguous 112-tile chunk (= 4 whole images).
    const int pt    = (blockIdx.x & 7) * 112 + (blockIdx.x >> 3);   // 0..895
    const int n_img = pt / 28;
    const int h0    = (pt % 28) * 2;   // output rows h0, h0+1

    // ---- fused staging: NCHW fp32 -> [ci_hi][pix][ci_lo] bf16 in LDS ----
    // wave wv handles input row h = h0-1+wv; 16 chunks of 8 ci x 58 cols.
    {
        const int h    = h0 - 1 + wv;
        const bool hval = ((unsigned)h < 56u);
        unsigned short* Lw = &Ls[wv][0];
        const float* xrow = x + (long)n_img * (CIN * IMG) + h * HWID;

        #pragma unroll 2
        for (int ci8 = 0; ci8 < 16; ++ci8) {
            // phase 1: 8 ci x 56 w, float4 coalesced (c4 0..13), pack bf16
            if (hval) {
                #pragma unroll
                for (int i = 0; i < 2; ++i) {
                    int flat = i * 64 + lane;      // 0..127
                    int cl   = flat >> 4;          // ci 0..7 within chunk
                    int c4   = flat & 15;          // float4 slot
                    if (c4 < 14) {
                        float4 v = *(const float4*)(xrow + ((long)(ci8 * 8 + cl)) * IMG + c4 * 4);
                        unsigned int lo = (unsigned int)f2bf(v.x) | ((unsigned int)f2bf(v.y) << 16);
                        unsigned int hi = (unsigned int)f2bf(v.z) | ((unsigned int)f2bf(v.w) << 16);
                        *(unsigned int*)(&Lw[cl * 66 + c4 * 4])     = lo;
                        *(unsigned int*)(&Lw[cl * 66 + c4 * 4 + 2]) = hi;
                    }
                }
            }
            // phase 2: transpose read (col c = lane, w = c-1), b128 write to Xs.
            // Same-wave DS ops are in-order; no barrier needed.
            int p_l = lane;                    // col 0..57 valid
            if (p_l < 58) {
                short8 o = (short8){0,0,0,0,0,0,0,0};
                if (hval && p_l > 0 && p_l < 57) {
                    #pragma unroll
                    for (int j = 0; j < 8; ++j)
                        o[j] = (short)Lw[j * 66 + (p_l - 1)];
                }
                int rc    = wv * 58 + p_l;
                int ci_hi = ci8 >> 2;
                *(short8*)(&Xs[ci_hi * XCH + rc * XP + (ci8 & 3) * 8]) = o;
            }
        }
    }
    __syncthreads();   // the only barrier

    // per-lane b-frag pixel bases, one per n-tile
    int boff[7];
    #pragma unroll
    for (int n = 0; n < 7; ++n) {
        int p    = n * 16 + l15;
        int prow = (p >= 56) ? 1 : 0;
        int pcol = p - prow * 56;
        boff[n]  = (prow * 58 + pcol) * XP + quad * 8;
    }

    // a-frag base: W2[step][co][ci_lo], co = wv*64 + m*16 + l15, ci_lo = quad*8+j
    const unsigned short* wbase = W2 + (wv * 64 + l15) * 32 + quad * 8;

    float4v acc[4][7];
    #pragma unroll
    for (int m = 0; m < 4; ++m)
        #pragma unroll
        for (int n = 0; n < 7; ++n)
            acc[m][n] = (float4v){0.f, 0.f, 0.f, 0.f};

    // A-fragment pipeline: a[] current step, an[] next step.
    short8 a[4], an[4];
    #pragma unroll
    for (int m = 0; m < 4; ++m)
        a[m] = *(const short8*)(wbase + m * 512);

    // ---- 36 steps, NO barriers ----
    #pragma unroll
    for (int ci_hi = 0; ci_hi < 4; ++ci_hi) {
        #pragma unroll
        for (int khw = 0; khw < 9; ++khw) {
            const int step = ci_hi * 9 + khw;
            const int kh = khw / 3, kw = khw - (khw / 3) * 3;
            if (step < 35) {
                #pragma unroll
                for (int m = 0; m < 4; ++m)
                    an[m] = *(const short8*)(wbase + (step + 1) * 8192 + m * 512);
            }
            short8 bfr[7];
            #pragma unroll
            for (int n = 0; n < 7; ++n)
                bfr[n] = *(const short8*)(&Xs[ci_hi * XCH + boff[n] + (kh * 58 + kw) * XP]);
            #pragma unroll
            for (int m = 0; m < 4; ++m)
                #pragma unroll
                for (int n = 0; n < 7; ++n)
                    acc[m][n] = __builtin_amdgcn_mfma_f32_16x16x32_bf16(a[m], bfr[n], acc[m][n], 0, 0, 0);
            if (step < 35) {
                #pragma unroll
                for (int m = 0; m < 4; ++m)
                    a[m] = an[m];
            }
        }
    }

    // ---- epilogue: C/D layout col(p)=lane&15, row(co)=quad*4+reg ----
    float* obase = out + (long)n_img * (COUT * IMG) + h0 * HWID;
    #pragma unroll
    for (int m = 0; m < 4; ++m) {
        #pragma unroll
        for (int r = 0; r < 4; ++r) {
            int co = wv * 64 + m * 16 + quad * 4 + r;
            float* orow = obase + (long)co * IMG;
            #pragma unroll
            for (int n = 0; n < 7; ++n)
                orow[n * 16 + l15] = acc[m][n][r];
        }
    }
}

extern "C" void kernel_launch(void* const* d_in, const int* in_sizes, int n_in,
                              void* d_out, int out_size, void* d_ws, size_t ws_size,
                              hipStream_t stream) {
    const float* x  = (const float*)d_in[0];
    const float* wt = (const float*)d_in[1];
    float* out = (float*)d_out;

    unsigned short* W2 = (unsigned short*)d_ws;   // 294,912 shorts

    prep_w_kernel<<<(COUT * CIN * 9) / 256, 256, 0, stream>>>(wt, W2);
    conv_mfma_kernel<<<NIMG * 28, 256, 0, stream>>>(x, W2, out);
}

// Round 5
// 183.507 us; speedup vs baseline: 1.0343x; 1.0343x over previous
//
#include <hip/hip_runtime.h>

// Conv2d 32x128x56x56 -> 32x256x56x56, 3x3, pad 1, stride 1. fp32 I/O.
// Implicit GEMM, bf16 mfma_f32_16x16x32.
// ROUND 5: fused staging redone as a REGISTER transpose (R4's per-wave LDS
// scratch transpose cost +29us: 208 LDS ops/lane + 16x serial
// load->wait->write->read chains). New staging: wave wv owns input row
// h = h0-1+wv; lane owns ONE pixel w = lane-1 (lanes 0..57, halo lanes
// write zeros). 16 rounds of {8 scalar f32 loads x[ci..ci+7][w] (lanes
// vary w at fixed ci => 64x4B fully coalesced), RNE-pack to short8 in
// registers, 1 ds_write_b128 to Xs}. Rounds independent => compiler
// pipelines with counted vmcnt. No scratch LDS, no transpose reads.
//   - Xs layout [ci_hi(4)][pixel(232)][ci_lo(32)], 64B pixel stride:
//     main-loop ds_read_b128 and staging writes both ~2-way banks = free.
//   - ONE barrier total; main loop = 36 steps {4 A global->reg prefetched
//     one step ahead, 7 ds_read_b128, 28 MFMA}, no barriers (R3 structure).
//   - XCD swizzle: 896 = 8*112, each XCD gets 4 whole images (halo
//     re-reads of x are same-XCD L2 hits).
// Block: 256 thr = 4 waves, tile 256co x 112p (2 output rows). Wave: 4m x 7n.
// LDS 59392 B -> 2 blocks/CU.

#define CIN   128
#define COUT  256
#define HWID  56
#define IMG   (HWID*HWID)     // 3136
#define NIMG  32
#define XP    32              // Xs pixel stride (shorts) = 64B
#define XCH   (232*XP)        // shorts per ci_hi plane

typedef __attribute__((ext_vector_type(8))) short short8;   // 8 bf16 = 4 VGPRs
typedef __attribute__((ext_vector_type(4))) float float4v;  // MFMA acc

__device__ __forceinline__ unsigned short f2bf(float f) {
    unsigned int u = __builtin_bit_cast(unsigned int, f);
    u += 0x7FFFu + ((u >> 16) & 1u);   // RNE
    return (unsigned short)(u >> 16);
}

// W2[((ci_hi*9 + kh*3 + kw)*256 + co)*32 + ci_lo] = bf16(w[co][ci_hi*32+ci_lo][kh][kw])
__global__ __launch_bounds__(256) void prep_w_kernel(const float* __restrict__ w,
                                                     unsigned short* __restrict__ W2) {
    int o = blockIdx.x * 256 + threadIdx.x;        // 294912 total
    int ci_lo = o & 31;
    int co    = (o >> 5) & 255;
    int s     = o >> 13;                           // 0..35
    int ci_hi = s / 9;
    int r9    = s - ci_hi * 9;                     // kh*3+kw
    W2[o] = f2bf(w[(co * CIN + ci_hi * 32 + ci_lo) * 9 + r9]);
}

__global__ __launch_bounds__(256, 2)
void conv_mfma_kernel(const float* __restrict__ x,
                      const unsigned short* __restrict__ W2,
                      float* __restrict__ out) {
    __shared__ __align__(16) unsigned short Xs[4 * XCH];   // 59392 B

    const int tid  = threadIdx.x;
    const int lane = tid & 63;
    const int wv   = tid >> 6;
    const int l15  = lane & 15;
    const int quad = lane >> 4;

    // XCD swizzle: blockIdx round-robins over 8 XCDs; give each XCD a
    // contiguous 112-tile chunk (= 4 whole images).
    const int pt    = (blockIdx.x & 7) * 112 + (blockIdx.x >> 3);   // 0..895
    const int n_img = pt / 28;
    const int h0    = (pt % 28) * 2;   // output rows h0, h0+1

    // ---- fused staging: register transpose, no scratch LDS ----
    // wave wv: input row h = h0-1+wv. lane: pixel w = lane-1 (c = lane).
    {
        const int h     = h0 - 1 + wv;
        const int wpix  = lane - 1;
        const bool vald = ((unsigned)h < 56u) & ((unsigned)wpix < 56u);
        const float* xcol = x + ((long)n_img * CIN) * IMG + h * HWID + wpix;
        const int rc = wv * 58 + lane;

        if (lane < 58) {
            #pragma unroll
            for (int c8 = 0; c8 < 16; ++c8) {
                short8 o = (short8){0,0,0,0,0,0,0,0};
                if (vald) {
                    float v0 = xcol[(c8*8 + 0) * IMG];
                    float v1 = xcol[(c8*8 + 1) * IMG];
                    float v2 = xcol[(c8*8 + 2) * IMG];
                    float v3 = xcol[(c8*8 + 3) * IMG];
                    float v4 = xcol[(c8*8 + 4) * IMG];
                    float v5 = xcol[(c8*8 + 5) * IMG];
                    float v6 = xcol[(c8*8 + 6) * IMG];
                    float v7 = xcol[(c8*8 + 7) * IMG];
                    unsigned int* op = (unsigned int*)&o;
                    op[0] = (unsigned int)f2bf(v0) | ((unsigned int)f2bf(v1) << 16);
                    op[1] = (unsigned int)f2bf(v2) | ((unsigned int)f2bf(v3) << 16);
                    op[2] = (unsigned int)f2bf(v4) | ((unsigned int)f2bf(v5) << 16);
                    op[3] = (unsigned int)f2bf(v6) | ((unsigned int)f2bf(v7) << 16);
                }
                *(short8*)(&Xs[(c8 >> 2) * XCH + rc * XP + (c8 & 3) * 8]) = o;
            }
        }
    }
    __syncthreads();   // the only barrier

    // per-lane b-frag pixel bases, one per n-tile
    int boff[7];
    #pragma unroll
    for (int n = 0; n < 7; ++n) {
        int p    = n * 16 + l15;
        int prow = (p >= 56) ? 1 : 0;
        int pcol = p - prow * 56;
        boff[n]  = (prow * 58 + pcol) * XP + quad * 8;
    }

    // a-frag base: W2[step][co][ci_lo], co = wv*64 + m*16 + l15, ci_lo = quad*8+j
    const unsigned short* wbase = W2 + (wv * 64 + l15) * 32 + quad * 8;

    float4v acc[4][7];
    #pragma unroll
    for (int m = 0; m < 4; ++m)
        #pragma unroll
        for (int n = 0; n < 7; ++n)
            acc[m][n] = (float4v){0.f, 0.f, 0.f, 0.f};

    // A-fragment pipeline: a[] current step, an[] next step.
    short8 a[4], an[4];
    #pragma unroll
    for (int m = 0; m < 4; ++m)
        a[m] = *(const short8*)(wbase + m * 512);

    // ---- 36 steps, NO barriers ----
    #pragma unroll
    for (int ci_hi = 0; ci_hi < 4; ++ci_hi) {
        #pragma unroll
        for (int khw = 0; khw < 9; ++khw) {
            const int step = ci_hi * 9 + khw;
            const int kh = khw / 3, kw = khw - (khw / 3) * 3;
            if (step < 35) {
                #pragma unroll
                for (int m = 0; m < 4; ++m)
                    an[m] = *(const short8*)(wbase + (step + 1) * 8192 + m * 512);
            }
            short8 bfr[7];
            #pragma unroll
            for (int n = 0; n < 7; ++n)
                bfr[n] = *(const short8*)(&Xs[ci_hi * XCH + boff[n] + (kh * 58 + kw) * XP]);
            #pragma unroll
            for (int m = 0; m < 4; ++m)
                #pragma unroll
                for (int n = 0; n < 7; ++n)
                    acc[m][n] = __builtin_amdgcn_mfma_f32_16x16x32_bf16(a[m], bfr[n], acc[m][n], 0, 0, 0);
            if (step < 35) {
                #pragma unroll
                for (int m = 0; m < 4; ++m)
                    a[m] = an[m];
            }
        }
    }

    // ---- epilogue: C/D layout col(p)=lane&15, row(co)=quad*4+reg ----
    float* obase = out + (long)n_img * (COUT * IMG) + h0 * HWID;
    #pragma unroll
    for (int m = 0; m < 4; ++m) {
        #pragma unroll
        for (int r = 0; r < 4; ++r) {
            int co = wv * 64 + m * 16 + quad * 4 + r;
            float* orow = obase + (long)co * IMG;
            #pragma unroll
            for (int n = 0; n < 7; ++n)
                orow[n * 16 + l15] = acc[m][n][r];
        }
    }
}

extern "C" void kernel_launch(void* const* d_in, const int* in_sizes, int n_in,
                              void* d_out, int out_size, void* d_ws, size_t ws_size,
                              hipStream_t stream) {
    const float* x  = (const float*)d_in[0];
    const float* wt = (const float*)d_in[1];
    float* out = (float*)d_out;

    unsigned short* W2 = (unsigned short*)d_ws;   // 294,912 shorts

    prep_w_kernel<<<(COUT * CIN * 9) / 256, 256, 0, stream>>>(wt, W2);
    conv_mfma_kernel<<<NIMG * 28, 256, 0, stream>>>(x, W2, out);
}

// Round 7
// 181.094 us; speedup vs baseline: 1.0481x; 1.0133x over previous
//
#include <hip/hip_runtime.h>

// Conv2d 32x128x56x56 -> 32x256x56x56, 3x3, pad 1, stride 1. fp32 I/O.
// Implicit GEMM, bf16 mfma_f32_16x16x32. Fused: conv stages straight from
// NCHW fp32 (no X2 intermediate); W2[step][co][ci_lo] prepped separately.
// ROUND 7 = ROUND 6 resubmitted (round 6 failed on container infra, kernel
// never ran):
//  1) B-fragment DOUBLE-BUFFER in the main loop: step s+1's 7 ds_read_b128
//     are issued before step s's 28 MFMAs, hiding LDS latency under the
//     matrix pipe. (A-frags were already pipelined; B was the exposed
//     dependency every step: MfmaUtil ceiling 38% across rounds 0-5.)
//     +28 VGPR -> ~240 unified, still 2 waves/SIMD.
//  2) Xs layout = R3's measured-best: flat [pixel][128ci] with RSTR=136
//     shorts (272B): 3.6M conflict cy vs 4.8M for the 64B layout (R4/R5).
//     ~3.6M of the counter is structural for b128 -- not the lever.
// Staging (R5 scheme): wave wv owns input row h = h0-1+wv, lane owns pixel
// w = lane-1 (lanes 0..57); 16 rounds of {8 coalesced scalar f32 loads,
// RNE pack to short8, ds_write_b128}. ONE barrier total; 36-step main loop
// barrier-free. XCD swizzle: 896 = 8*112, each XCD gets 4 whole images.
// Block: 256 thr = 4 waves, tile 256co x 112p (2 output rows). Wave: 4m x 7n.

#define CIN   128
#define COUT  256
#define HWID  56
#define IMG   (HWID*HWID)     // 3136
#define NIMG  32
#define RSTR  136             // Xs pixel stride in shorts (272B, 16B-aligned)

typedef __attribute__((ext_vector_type(8))) short short8;   // 8 bf16 = 4 VGPRs
typedef __attribute__((ext_vector_type(4))) float float4v;  // MFMA acc

__device__ __forceinline__ unsigned short f2bf(float f) {
    unsigned int u = __builtin_bit_cast(unsigned int, f);
    u += 0x7FFFu + ((u >> 16) & 1u);   // RNE
    return (unsigned short)(u >> 16);
}

// W2[((ci_hi*9 + kh*3 + kw)*256 + co)*32 + ci_lo] = bf16(w[co][ci_hi*32+ci_lo][kh][kw])
__global__ __launch_bounds__(256) void prep_w_kernel(const float* __restrict__ w,
                                                     unsigned short* __restrict__ W2) {
    int o = blockIdx.x * 256 + threadIdx.x;        // 294912 total
    int ci_lo = o & 31;
    int co    = (o >> 5) & 255;
    int s     = o >> 13;                           // 0..35
    int ci_hi = s / 9;
    int r9    = s - ci_hi * 9;                     // kh*3+kw
    W2[o] = f2bf(w[(co * CIN + ci_hi * 32 + ci_lo) * 9 + r9]);
}

__global__ __launch_bounds__(256, 2)
void conv_mfma_kernel(const float* __restrict__ x,
                      const unsigned short* __restrict__ W2,
                      float* __restrict__ out) {
    __shared__ __align__(16) unsigned short Xs[232 * RSTR];   // 63104 B

    const int tid  = threadIdx.x;
    const int lane = tid & 63;
    const int wv   = tid >> 6;
    const int l15  = lane & 15;
    const int quad = lane >> 4;

    // XCD swizzle: give each XCD a contiguous 112-tile chunk (4 whole images).
    const int pt    = (blockIdx.x & 7) * 112 + (blockIdx.x >> 3);   // 0..895
    const int n_img = pt / 28;
    const int h0    = (pt % 28) * 2;   // output rows h0, h0+1

    // ---- fused staging: register transpose, no scratch LDS ----
    // wave wv: input row h = h0-1+wv. lane: pixel w = lane-1 (c = lane).
    {
        const int h     = h0 - 1 + wv;
        const int wpix  = lane - 1;
        const bool vald = ((unsigned)h < 56u) & ((unsigned)wpix < 56u);
        const float* xcol = x + ((long)n_img * CIN) * IMG + h * HWID + wpix;
        const int rc = wv * 58 + lane;

        if (lane < 58) {
            #pragma unroll
            for (int c8 = 0; c8 < 16; ++c8) {
                short8 o = (short8){0,0,0,0,0,0,0,0};
                if (vald) {
                    float v0 = xcol[(c8*8 + 0) * IMG];
                    float v1 = xcol[(c8*8 + 1) * IMG];
                    float v2 = xcol[(c8*8 + 2) * IMG];
                    float v3 = xcol[(c8*8 + 3) * IMG];
                    float v4 = xcol[(c8*8 + 4) * IMG];
                    float v5 = xcol[(c8*8 + 5) * IMG];
                    float v6 = xcol[(c8*8 + 6) * IMG];
                    float v7 = xcol[(c8*8 + 7) * IMG];
                    unsigned int* op = (unsigned int*)&o;
                    op[0] = (unsigned int)f2bf(v0) | ((unsigned int)f2bf(v1) << 16);
                    op[1] = (unsigned int)f2bf(v2) | ((unsigned int)f2bf(v3) << 16);
                    op[2] = (unsigned int)f2bf(v4) | ((unsigned int)f2bf(v5) << 16);
                    op[3] = (unsigned int)f2bf(v6) | ((unsigned int)f2bf(v7) << 16);
                }
                *(short8*)(&Xs[rc * RSTR + c8 * 8]) = o;
            }
        }
    }
    __syncthreads();   // the only barrier

    // per-lane b-frag pixel bases, one per n-tile
    int boff[7];
    #pragma unroll
    for (int n = 0; n < 7; ++n) {
        int p    = n * 16 + l15;
        int prow = (p >= 56) ? 1 : 0;
        int pcol = p - prow * 56;
        boff[n]  = (prow * 58 + pcol) * RSTR + quad * 8;
    }

    // a-frag base: W2[step][co][ci_lo], co = wv*64 + m*16 + l15, ci_lo = quad*8+j
    const unsigned short* wbase = W2 + (wv * 64 + l15) * 32 + quad * 8;

    float4v acc[4][7];
    #pragma unroll
    for (int m = 0; m < 4; ++m)
        #pragma unroll
        for (int n = 0; n < 7; ++n)
            acc[m][n] = (float4v){0.f, 0.f, 0.f, 0.f};

    // Double-buffered operand pipelines: a/an (A, global), b0/b1 (B, LDS).
    short8 a[4], an[4], b0[7], b1[7];
    #pragma unroll
    for (int m = 0; m < 4; ++m)
        a[m] = *(const short8*)(wbase + m * 512);
    #pragma unroll
    for (int n = 0; n < 7; ++n)
        b0[n] = *(const short8*)(&Xs[boff[n]]);   // step 0: ci_hi=0, kh=kw=0

    // ---- 36 steps, NO barriers. B-frags for step s+1 issued before the
    // MFMAs of step s (latency hidden under the matrix pipe). Loop is fully
    // unrolled: s is compile-time constant, b0/b1 accesses statically
    // indexed (no scratch). ----
    #pragma unroll
    for (int s = 0; s < 36; ++s) {
        if (s < 35) {
            const int s1     = s + 1;
            const int ci_hi1 = s1 / 9;
            const int khw1   = s1 % 9;
            const int kh1 = khw1 / 3, kw1 = khw1 - kh1 * 3;
            const int xoff1  = (kh1 * 58 + kw1) * RSTR + ci_hi1 * 32;
            if (s & 1) {
                #pragma unroll
                for (int n = 0; n < 7; ++n)
                    b0[n] = *(const short8*)(&Xs[boff[n] + xoff1]);
            } else {
                #pragma unroll
                for (int n = 0; n < 7; ++n)
                    b1[n] = *(const short8*)(&Xs[boff[n] + xoff1]);
            }
            #pragma unroll
            for (int m = 0; m < 4; ++m)
                an[m] = *(const short8*)(wbase + s1 * 8192 + m * 512);
        }
        #pragma unroll
        for (int m = 0; m < 4; ++m) {
            #pragma unroll
            for (int n = 0; n < 7; ++n) {
                const short8 bf = (s & 1) ? b1[n] : b0[n];
                acc[m][n] = __builtin_amdgcn_mfma_f32_16x16x32_bf16(a[m], bf, acc[m][n], 0, 0, 0);
            }
        }
        if (s < 35) {
            #pragma unroll
            for (int m = 0; m < 4; ++m)
                a[m] = an[m];
        }
    }

    // ---- epilogue: C/D layout col(p)=lane&15, row(co)=quad*4+reg ----
    float* obase = out + (long)n_img * (COUT * IMG) + h0 * HWID;
    #pragma unroll
    for (int m = 0; m < 4; ++m) {
        #pragma unroll
        for (int r = 0; r < 4; ++r) {
            int co = wv * 64 + m * 16 + quad * 4 + r;
            float* orow = obase + (long)co * IMG;
            #pragma unroll
            for (int n = 0; n < 7; ++n)
                orow[n * 16 + l15] = acc[m][n][r];
        }
    }
}

extern "C" void kernel_launch(void* const* d_in, const int* in_sizes, int n_in,
                              void* d_out, int out_size, void* d_ws, size_t ws_size,
                              hipStream_t stream) {
    const float* x  = (const float*)d_in[0];
    const float* wt = (const float*)d_in[1];
    float* out = (float*)d_out;

    unsigned short* W2 = (unsigned short*)d_ws;   // 294,912 shorts

    prep_w_kernel<<<(COUT * CIN * 9) / 256, 256, 0, stream>>>(wt, W2);
    conv_mfma_kernel<<<NIMG * 28, 256, 0, stream>>>(x, W2, out);
}